// Round 17
// baseline (286.360 us; speedup 1.0000x reference)
//
#include <hip/hip_runtime.h>
#include <math.h>

#define HDIM 128

typedef __attribute__((ext_vector_type(8))) short bf16x8;
typedef __attribute__((ext_vector_type(4))) float f32x4;
typedef __attribute__((ext_vector_type(4))) _Float16 h16x4;
typedef __attribute__((ext_vector_type(8))) _Float16 h16x8;

// RNE split of fp32 into bf16 hi + bf16 lo (x ~= hi + lo, err ~2^-16 |x|)
__device__ __forceinline__ void split_bf16(float x, short& hi, short& lo) {
    unsigned u = __float_as_uint(x);
    unsigned r = (u + 0x7FFFu + ((u >> 16) & 1u)) >> 16;
    float hf = __uint_as_float(r << 16);
    hi = (short)r;
    float l = x - hf;
    unsigned ul = __float_as_uint(l);
    unsigned rl = (ul + 0x7FFFu + ((ul >> 16) & 1u)) >> 16;
    lo = (short)rl;
}

__device__ __forceinline__ unsigned pack2(short a, short b) {
    return (unsigned)(unsigned short)a | ((unsigned)(unsigned short)b << 16);
}

// ---------------- degree histogram + unique slot capture ----------------
__global__ __launch_bounds__(256) void deg_hist_k(const int* __restrict__ col,
                                                  int* __restrict__ deg,
                                                  int* __restrict__ slot, int E) {
    int e = blockIdx.x * 256 + threadIdx.x;
    if (e < E) slot[e] = atomicAdd(&deg[col[e]], 1);
}

// ---------------- scan1 + degree finish (fused) ----------------
__global__ __launch_bounds__(256) void scan1_k(const int* __restrict__ deg,
                                               int* __restrict__ incl,
                                               int* __restrict__ partial,
                                               float* __restrict__ dis,
                                               float* __restrict__ dinv, int N) {
    int i = blockIdx.x * 256 + threadIdx.x;
    int lane = threadIdx.x & 63;
    int wid = threadIdx.x >> 6;
    int d0 = (i < N) ? deg[i] : 0;
    if (i < N) {
        double d = (double)d0 + 1.0;
        dis[i]  = (float)(1.0 / sqrt(d));
        dinv[i] = (float)(1.0 / d);
    }
    int s = d0;
#pragma unroll
    for (int off = 1; off < 64; off <<= 1) {
        int t = __shfl_up(s, off);
        if (lane >= off) s += t;
    }
    __shared__ int wsum[4];
    if (lane == 63) wsum[wid] = s;
    __syncthreads();
    if (threadIdx.x == 0) {
        int run = 0;
#pragma unroll
        for (int w = 0; w < 4; ++w) { int t = wsum[w]; wsum[w] = run; run += t; }
    }
    __syncthreads();
    s += wsum[wid];
    if (i < N) incl[i] = s;
    if (threadIdx.x == 255) partial[blockIdx.x] = s;
}

__global__ __launch_bounds__(512) void scan2_k(int* __restrict__ partial, int NB) {
    __shared__ int sm[512];
    int t = threadIdx.x;
    sm[t] = (t < NB) ? partial[t] : 0;
    __syncthreads();
    for (int off = 1; off < 512; off <<= 1) {
        int v = (t >= off) ? sm[t - off] : 0;
        __syncthreads();
        sm[t] += v;
        __syncthreads();
    }
    if (t < NB) partial[t] = (t == 0) ? 0 : sm[t - 1];
}

__global__ __launch_bounds__(256) void scan3_k(const int* __restrict__ deg,
                                               const int* __restrict__ incl,
                                               const int* __restrict__ partial,
                                               int* __restrict__ row_ptr, int N) {
    int i = blockIdx.x * 256 + threadIdx.x;
    if (i < N) {
        int off = partial[blockIdx.x];
        row_ptr[i] = incl[i] - deg[i] + off;
        if (i == N - 1) row_ptr[N] = incl[i] + off;
    }
}

// ---------------- CSR fill: atomic-free (slot from deg_hist) ----------------
__global__ __launch_bounds__(256) void fill_k(const int* __restrict__ row,
                                              const int* __restrict__ col,
                                              const int* __restrict__ slot,
                                              const float* __restrict__ dis,
                                              const int* __restrict__ row_ptr,
                                              int2* __restrict__ csr, int E) {
    int e = blockIdx.x * 256 + threadIdx.x;
    if (e >= E) return;
    int c = col[e];
    int r = row[e];
    float nrm = dis[r] * dis[c];
    csr[row_ptr[c] + slot[e]] = make_int2(r, __float_as_int(nrm));
}

// ---------------- X fp32 -> fp16 ----------------
__global__ __launch_bounds__(256) void xcvt_k(const float* __restrict__ X,
                                              _Float16* __restrict__ xh, int n4) {
    int i = blockIdx.x * 256 + threadIdx.x;
    if (i < n4) {
        float4 v = *reinterpret_cast<const float4*>(X + (size_t)i * 4);
        h16x4 h = {(_Float16)v.x, (_Float16)v.y, (_Float16)v.z, (_Float16)v.w};
        *reinterpret_cast<h16x4*>(xh + (size_t)i * 4) = h;
    }
}

// ---------------- W pre-split: W[K][128] -> T_hi/lo[n][k] (bf16 shorts) ----------------
__global__ __launch_bounds__(256) void wsplit_k(const float* __restrict__ W,
                                                short* __restrict__ Thi,
                                                short* __restrict__ Tlo, int K) {
    int idx = blockIdx.x * 256 + threadIdx.x;
    if (idx < K * 128) {
        int k = idx >> 7, n = idx & 127;
        short h, l; split_bf16(W[idx], h, l);
        Thi[n * K + k] = h; Tlo[n * K + k] = l;
    }
}

// ---------------- chunked split-bf16 MFMA GEMM ----------------
// AMODE: false = fp32 A (XF, split on stage); true = pre-split A (AHi/ALo bf16 row-major)
// OSPLIT: true = epilogue applies relu and writes OutHi/OutLo bf16 split; false = fp16 outH
template<int K, bool BIAS, bool ASPLIT, bool OSPLIT>
__global__ __launch_bounds__(256) void gemm_mfma2(const float* __restrict__ XF,
                                                  const short* __restrict__ AHi,
                                                  const short* __restrict__ ALo,
                                                  const short* __restrict__ WThi,
                                                  const short* __restrict__ WTlo,
                                                  const float* __restrict__ b,
                                                  short* __restrict__ OutHi,
                                                  short* __restrict__ OutLo,
                                                  _Float16* __restrict__ outH, int N) {
    constexpr int KP = 40;
    __shared__ short ahi[128][KP], alo[128][KP];
    __shared__ short bhi[128][KP], blo[128][KP];
    const int tid = threadIdx.x;
    const int wid = tid >> 6, lane = tid & 63;
    const int lr = lane & 15;
    const int lk = (lane >> 4) * 8;
    const int m0b = blockIdx.x * 128;

    f32x4 acc[2][8];
#pragma unroll
    for (int rt = 0; rt < 2; ++rt)
#pragma unroll
        for (int ct = 0; ct < 8; ++ct) acc[rt][ct] = (f32x4){0.f, 0.f, 0.f, 0.f};

    for (int ch = 0; ch < K / 32; ++ch) {
        __syncthreads();
        if (ASPLIT) {
            // stage pre-split A: pure 16B copies (no VALU split work)
#pragma unroll
            for (int i = 0; i < 2; ++i) {
                int f = tid + i * 256;           // 0..511
                int r = f >> 2, k8 = (f & 3) * 8;
                int grow = m0b + r;
                uint4 vh = make_uint4(0u, 0u, 0u, 0u), vl = make_uint4(0u, 0u, 0u, 0u);
                if (grow < N) {
                    vh = *reinterpret_cast<const uint4*>(AHi + (size_t)grow * K + ch * 32 + k8);
                    vl = *reinterpret_cast<const uint4*>(ALo + (size_t)grow * K + ch * 32 + k8);
                }
                *reinterpret_cast<uint4*>(&ahi[r][k8]) = vh;
                *reinterpret_cast<uint4*>(&alo[r][k8]) = vl;
            }
        } else {
            // stage A from fp32 with on-the-fly split
#pragma unroll
            for (int i = 0; i < 4; ++i) {
                int f = tid + i * 256;           // 0..1023
                int r = f >> 3, kq = f & 7;
                int grow = m0b + r;
                float4 v = make_float4(0.f, 0.f, 0.f, 0.f);
                if (grow < N) v = *reinterpret_cast<const float4*>(XF + (size_t)grow * K + ch * 32 + kq * 4);
                short hA, lA, hB, lB;
                split_bf16(v.x, hA, lA); split_bf16(v.y, hB, lB);
                *reinterpret_cast<unsigned*>(&ahi[r][kq * 4])     = pack2(hA, hB);
                *reinterpret_cast<unsigned*>(&alo[r][kq * 4])     = pack2(lA, lB);
                split_bf16(v.z, hA, lA); split_bf16(v.w, hB, lB);
                *reinterpret_cast<unsigned*>(&ahi[r][kq * 4 + 2]) = pack2(hA, hB);
                *reinterpret_cast<unsigned*>(&alo[r][kq * 4 + 2]) = pack2(lA, lB);
            }
        }
        // stage B: pre-split WT rows, 16B copies
#pragma unroll
        for (int i = 0; i < 2; ++i) {
            int f = tid + i * 256;               // 0..511
            int n = f >> 2, k8 = (f & 3) * 8;
            *reinterpret_cast<uint4*>(&bhi[n][k8]) =
                *reinterpret_cast<const uint4*>(WThi + (size_t)n * K + ch * 32 + k8);
            *reinterpret_cast<uint4*>(&blo[n][k8]) =
                *reinterpret_cast<const uint4*>(WTlo + (size_t)n * K + ch * 32 + k8);
        }
        __syncthreads();

        bf16x8 Ahi[2], Alo[2];
#pragma unroll
        for (int rt = 0; rt < 2; ++rt) {
            int arow = wid * 32 + rt * 16 + lr;
            Ahi[rt] = *reinterpret_cast<const bf16x8*>(&ahi[arow][lk]);
            Alo[rt] = *reinterpret_cast<const bf16x8*>(&alo[arow][lk]);
        }
#pragma unroll
        for (int ct = 0; ct < 8; ++ct) {
            bf16x8 Bhi = *reinterpret_cast<const bf16x8*>(&bhi[ct * 16 + lr][lk]);
            bf16x8 Blo = *reinterpret_cast<const bf16x8*>(&blo[ct * 16 + lr][lk]);
#pragma unroll
            for (int rt = 0; rt < 2; ++rt) {
                acc[rt][ct] = __builtin_amdgcn_mfma_f32_16x16x32_bf16(Ahi[rt], Bhi, acc[rt][ct], 0, 0, 0);
                acc[rt][ct] = __builtin_amdgcn_mfma_f32_16x16x32_bf16(Ahi[rt], Blo, acc[rt][ct], 0, 0, 0);
                acc[rt][ct] = __builtin_amdgcn_mfma_f32_16x16x32_bf16(Alo[rt], Bhi, acc[rt][ct], 0, 0, 0);
            }
        }
    }

    const int r0 = (lane >> 4) * 4;
#pragma unroll
    for (int ct = 0; ct < 8; ++ct) {
        float bias = BIAS ? b[ct * 16 + lr] : 0.f;
#pragma unroll
        for (int rt = 0; rt < 2; ++rt) {
#pragma unroll
            for (int r = 0; r < 4; ++r) {
                int rowi = m0b + wid * 32 + rt * 16 + r0 + r;
                if (rowi < N) {
                    float val = acc[rt][ct][r] + bias;
                    size_t idx = (size_t)rowi * HDIM + ct * 16 + lr;
                    if (OSPLIT) {
                        float rl = fmaxf(val, 0.f);     // relu applied here (h1 only used as relu(h1))
                        short h, l; split_bf16(rl, h, l);
                        OutHi[idx] = h; OutLo[idx] = l;
                    } else {
                        outH[idx] = (_Float16)val;
                    }
                }
            }
        }
    }
}

// ---------------- 32-dim input gather (octant, fp16 X, int2 csr w/ norm) ----------------
__global__ __launch_bounds__(256) void gather_x_k(const int* __restrict__ row_ptr,
                                                  const int2* __restrict__ csr,
                                                  const float* __restrict__ dinv,
                                                  const _Float16* __restrict__ xh,
                                                  float* __restrict__ Y, int N) {
    int idx = blockIdx.x * 256 + threadIdx.x;
    int c = idx >> 3;
    if (c >= N) return;
    int hq = idx & 7;
    int j0 = row_ptr[c], j1 = row_ptr[c + 1];
    float di = dinv[c];
    h16x4 xc = *reinterpret_cast<const h16x4*>(xh + (size_t)c * 32 + hq * 4);
    float4 acc = make_float4(di * (float)xc[0], di * (float)xc[1],
                             di * (float)xc[2], di * (float)xc[3]);
    int j = j0;
    for (; j + 3 < j1; j += 4) {
        int2 e0 = csr[j], e1 = csr[j + 1], e2 = csr[j + 2], e3 = csr[j + 3];
        h16x4 v0 = *reinterpret_cast<const h16x4*>(xh + (size_t)e0.x * 32 + hq * 4);
        h16x4 v1 = *reinterpret_cast<const h16x4*>(xh + (size_t)e1.x * 32 + hq * 4);
        h16x4 v2 = *reinterpret_cast<const h16x4*>(xh + (size_t)e2.x * 32 + hq * 4);
        h16x4 v3 = *reinterpret_cast<const h16x4*>(xh + (size_t)e3.x * 32 + hq * 4);
        float n0 = __int_as_float(e0.y), n1 = __int_as_float(e1.y);
        float n2 = __int_as_float(e2.y), n3 = __int_as_float(e3.y);
        acc.x += n0 * (float)v0[0] + n1 * (float)v1[0] + n2 * (float)v2[0] + n3 * (float)v3[0];
        acc.y += n0 * (float)v0[1] + n1 * (float)v1[1] + n2 * (float)v2[1] + n3 * (float)v3[1];
        acc.z += n0 * (float)v0[2] + n1 * (float)v1[2] + n2 * (float)v2[2] + n3 * (float)v3[2];
        acc.w += n0 * (float)v0[3] + n1 * (float)v1[3] + n2 * (float)v2[3] + n3 * (float)v3[3];
    }
    for (; j < j1; ++j) {
        int2 en = csr[j];
        float nrm = __int_as_float(en.y);
        h16x4 v = *reinterpret_cast<const h16x4*>(xh + (size_t)en.x * 32 + hq * 4);
        acc.x += nrm * (float)v[0]; acc.y += nrm * (float)v[1];
        acc.z += nrm * (float)v[2]; acc.w += nrm * (float)v[3];
    }
    *reinterpret_cast<float4*>(Y + (size_t)c * 32 + hq * 4) = acc;
}

// ---------------- w3l = W3 @ Wlin ; consts[0] = b3.Wlin + blin ----------------
__global__ __launch_bounds__(128) void w3l_k(const float* __restrict__ W3,
                                             const float* __restrict__ b3,
                                             const float* __restrict__ Wlin,
                                             const float* __restrict__ blin,
                                             float* __restrict__ w3l,
                                             float* __restrict__ consts) {
    __shared__ float wl[128];
    __shared__ float red[128];
    int t = threadIdx.x;
    wl[t] = Wlin[t];
    __syncthreads();
    float a = 0.f;
    for (int j = 0; j < 128; ++j) a += W3[t * 128 + j] * wl[j];
    w3l[t] = a;
    red[t] = b3[t] * wl[t];
    __syncthreads();
    for (int off = 64; off > 0; off >>= 1) {
        if (t < off) red[t] += red[t + off];
        __syncthreads();
    }
    if (t == 0) consts[0] = red[0] + blin[0];
}

// ---------------- fused layer-2 gather (fp16 xw, int2 csr) + z projection ----------------
__global__ __launch_bounds__(256) void gather_z_k(const int* __restrict__ row_ptr,
                                                  const int2* __restrict__ csr,
                                                  const float* __restrict__ dinv,
                                                  const float* __restrict__ b,
                                                  const _Float16* __restrict__ xw,
                                                  const float* __restrict__ w3l,
                                                  float* __restrict__ z, int N) {
    int c = (blockIdx.x * 256 + threadIdx.x) >> 6;
    if (c >= N) return;
    int lane = threadIdx.x & 63;
    int g = lane >> 4;          // edge slot 0..3
    int q = lane & 15;          // 8-elem chunk of the 128-dim row
    int j0 = row_ptr[c], j1 = row_ptr[c + 1];
    float acc[8] = {0.f, 0.f, 0.f, 0.f, 0.f, 0.f, 0.f, 0.f};
    int j = j0 + g;
    for (; j + 4 < j1; j += 8) {
        int2 e0 = csr[j], e1 = csr[j + 4];
        float n0 = __int_as_float(e0.y), n1 = __int_as_float(e1.y);
        h16x8 v0 = *reinterpret_cast<const h16x8*>(xw + (size_t)e0.x * HDIM + q * 8);
        h16x8 v1 = *reinterpret_cast<const h16x8*>(xw + (size_t)e1.x * HDIM + q * 8);
#pragma unroll
        for (int k = 0; k < 8; ++k) acc[k] += n0 * (float)v0[k] + n1 * (float)v1[k];
    }
    for (; j < j1; j += 4) {
        int2 en = csr[j];
        float nrm = __int_as_float(en.y);
        h16x8 v = *reinterpret_cast<const h16x8*>(xw + (size_t)en.x * HDIM + q * 8);
#pragma unroll
        for (int k = 0; k < 8; ++k) acc[k] += nrm * (float)v[k];
    }
#pragma unroll
    for (int k = 0; k < 8; ++k) {
        acc[k] += __shfl_xor(acc[k], 16);
        acc[k] += __shfl_xor(acc[k], 32);
    }
    h16x8 xc = *reinterpret_cast<const h16x8*>(xw + (size_t)c * HDIM + q * 8);
    float di = dinv[c];
    float4 b0 = *reinterpret_cast<const float4*>(b + q * 8);
    float4 b1 = *reinterpret_cast<const float4*>(b + q * 8 + 4);
    float4 w0 = *reinterpret_cast<const float4*>(w3l + q * 8);
    float4 w1 = *reinterpret_cast<const float4*>(w3l + q * 8 + 4);
    const float bb[8] = {b0.x, b0.y, b0.z, b0.w, b1.x, b1.y, b1.z, b1.w};
    const float ww[8] = {w0.x, w0.y, w0.z, w0.w, w1.x, w1.y, w1.z, w1.w};
    float t = 0.f;
#pragma unroll
    for (int k = 0; k < 8; ++k)
        t += fmaxf(di * (float)xc[k] + bb[k] + acc[k], 0.f) * ww[k];
#pragma unroll
    for (int off = 1; off < 16; off <<= 1) t += __shfl_xor(t, off);
    if (lane == 0) z[c] = t;
}

// ---------------- scalar layer-3 gather (int2 csr) ----------------
__global__ __launch_bounds__(256) void gather_s_k(const int* __restrict__ row_ptr,
                                                  const int2* __restrict__ csr,
                                                  const float* __restrict__ dinv,
                                                  const float* __restrict__ z,
                                                  float* __restrict__ s, int N) {
    int c = blockIdx.x * 256 + threadIdx.x;
    if (c >= N) return;
    int j0 = row_ptr[c], j1 = row_ptr[c + 1];
    float acc = dinv[c] * z[c];
    for (int j = j0; j < j1; ++j) {
        int2 en = csr[j];
        acc += __int_as_float(en.y) * z[en.x];
    }
    s[c] = acc;
}

// ---------------- graph start offsets (batch is sorted) ----------------
__global__ __launch_bounds__(256) void gstart_k(const int* __restrict__ batch,
                                                int* __restrict__ start, int N, int G) {
    int n = blockIdx.x * 256 + threadIdx.x;
    if (n > N) return;
    if (n < N) {
        int b = batch[n];
        int prev = (n == 0) ? -1 : batch[n - 1];
        for (int g = prev + 1; g <= b; ++g) start[g] = n;
    } else {
        int prev = batch[N - 1];
        for (int g = prev + 1; g <= G; ++g) start[g] = N;
    }
}

// ---------------- final: out[g] = mean_{c in g} s[c] + consts[0] ----------------
__global__ __launch_bounds__(256) void final_z_k(const float* __restrict__ s,
                                                 const int* __restrict__ start,
                                                 const float* __restrict__ consts,
                                                 const float* __restrict__ blin,
                                                 float* __restrict__ out, int G) {
    int g = blockIdx.x * 4 + (threadIdx.x >> 6);
    int lane = threadIdx.x & 63;
    if (g >= G) return;
    int a = start[g], e = start[g + 1];
    float acc = 0.f;
    for (int n = a + lane; n < e; n += 64) acc += s[n];
#pragma unroll
    for (int off = 32; off > 0; off >>= 1) acc += __shfl_down(acc, off);
    if (lane == 0) out[g] = (e > a) ? acc / (float)(e - a) + consts[0] : blin[0];
}

extern "C" void kernel_launch(void* const* d_in, const int* in_sizes, int n_in,
                              void* d_out, int out_size, void* d_ws, size_t ws_size,
                              hipStream_t stream) {
    const float* x    = (const float*)d_in[0];
    const float* W1   = (const float*)d_in[1];
    const float* b1   = (const float*)d_in[2];
    const float* W2   = (const float*)d_in[3];
    const float* b2   = (const float*)d_in[4];
    const float* W3   = (const float*)d_in[5];
    const float* b3   = (const float*)d_in[6];
    const float* Wlin = (const float*)d_in[7];
    const float* blin = (const float*)d_in[8];
    const int* ei     = (const int*)d_in[9];
    const int* batch  = (const int*)d_in[10];

    const int N = in_sizes[10];
    const int E = in_sizes[9] / 2;
    const int G = out_size;
    const size_t NH = (size_t)N * HDIM;
    const int NB = (N + 255) / 256;

    const int* row = ei;
    const int* col = ei + E;

    int2* csr      = (int2*)d_ws;                    // [E] {src, nrm}
    _Float16* xh   = (_Float16*)(csr + E);           // [N,32] fp16
    float* Y       = (float*)(xh + (size_t)N * 32);  // [N,32] fp32
    short* h1hi    = (short*)(Y + (size_t)N * 32);   // [N,128] bf16 hi (relu'd)
    short* h1lo    = h1hi + NH;                      // [N,128] bf16 lo
    _Float16* xwh  = (_Float16*)(h1lo + NH);         // [N,128] fp16
    float* dis     = (float*)(xwh + NH);             // [N]
    float* dinv    = dis + N;                        // [N]
    float* zbuf    = dinv + N;                       // [N]
    float* sbuf    = zbuf + N;                       // [N]
    float* w3l     = sbuf + N;                       // [128]
    float* consts  = w3l + 128;                      // [4]
    short* w1hi    = (short*)(consts + 4);           // [128*32]
    short* w1lo    = w1hi + 128 * 32;
    short* w2hi    = w1lo + 128 * 32;                // [128*128]
    short* w2lo    = w2hi + 128 * 128;
    int* deg_i     = (int*)(w2lo + 128 * 128);       // [N]
    int* row_ptr   = deg_i + N;                      // [N+1]
    int* slot      = row_ptr + N + 1;                // [E]
    int* gstart    = slot + E;                       // [G+1]
    int* incl      = gstart + G + 1;                 // [N]
    int* partial   = incl + N;                       // [NB]

    float* outf = (float*)d_out;

    // ---- CSR build + weight prep ----
    hipMemsetAsync(deg_i, 0, (size_t)N * sizeof(int), stream);
    deg_hist_k<<<(E + 255) / 256, 256, 0, stream>>>(col, deg_i, slot, E);
    scan1_k<<<NB, 256, 0, stream>>>(deg_i, incl, partial, dis, dinv, N);
    scan2_k<<<1, 512, 0, stream>>>(partial, NB);
    scan3_k<<<NB, 256, 0, stream>>>(deg_i, incl, partial, row_ptr, N);
    fill_k<<<(E + 255) / 256, 256, 0, stream>>>(row, col, slot, dis, row_ptr, csr, E);
    gstart_k<<<(N + 256) / 256, 256, 0, stream>>>(batch, gstart, N, G);
    xcvt_k<<<(N * 8 + 255) / 256, 256, 0, stream>>>(x, xh, N * 8);
    wsplit_k<<<(32 * 128 + 255) / 256, 256, 0, stream>>>(W1, w1hi, w1lo, 32);
    wsplit_k<<<(128 * 128 + 255) / 256, 256, 0, stream>>>(W2, w2hi, w2lo, 128);
    w3l_k<<<1, 128, 0, stream>>>(W3, b3, Wlin, blin, w3l, consts);

    const int mfma_grid = (N + 127) / 128;
    const int wave_grid = (N + 3) / 4;

    // layer 1: Y = A_hat xh ; h1 = relu(Y W1 + b1) stored pre-split bf16 hi/lo
    gather_x_k<<<(N * 8 + 255) / 256, 256, 0, stream>>>(row_ptr, csr, dinv, xh, Y, N);
    gemm_mfma2<32, true, false, true><<<mfma_grid, 256, 0, stream>>>(
        Y, nullptr, nullptr, w1hi, w1lo, b1, h1hi, h1lo, nullptr, N);
    // layer 2: xwh = h1 W2 (pre-split A, pure-copy staging) ; fused gather(+b2) + z
    gemm_mfma2<128, false, true, false><<<mfma_grid, 256, 0, stream>>>(
        nullptr, h1hi, h1lo, w2hi, w2lo, nullptr, nullptr, nullptr, xwh, N);
    gather_z_k<<<wave_grid, 256, 0, stream>>>(row_ptr, csr, dinv, b2, xwh, w3l, zbuf, N);
    // layer 3 (collapsed): s = dinv*z + A-gather(z)
    gather_s_k<<<(N + 255) / 256, 256, 0, stream>>>(row_ptr, csr, dinv, zbuf, sbuf, N);
    // final: segment mean + consts
    final_z_k<<<(G + 3) / 4, 256, 0, stream>>>(sbuf, gstart, consts, blin, outf, G);
}

// Round 18
// 276.417 us; speedup vs baseline: 1.0360x; 1.0360x over previous
//
#include <hip/hip_runtime.h>
#include <math.h>

#define HDIM 128

typedef __attribute__((ext_vector_type(8))) short bf16x8;
typedef __attribute__((ext_vector_type(4))) float f32x4;
typedef __attribute__((ext_vector_type(4))) _Float16 h16x4;
typedef __attribute__((ext_vector_type(8))) _Float16 h16x8;

// RNE split of fp32 into bf16 hi + bf16 lo (x ~= hi + lo; exact for fp16 inputs)
__device__ __forceinline__ void split_bf16(float x, short& hi, short& lo) {
    unsigned u = __float_as_uint(x);
    unsigned r = (u + 0x7FFFu + ((u >> 16) & 1u)) >> 16;
    float hf = __uint_as_float(r << 16);
    hi = (short)r;
    float l = x - hf;
    unsigned ul = __float_as_uint(l);
    unsigned rl = (ul + 0x7FFFu + ((ul >> 16) & 1u)) >> 16;
    lo = (short)rl;
}

__device__ __forceinline__ unsigned pack2(short a, short b) {
    return (unsigned)(unsigned short)a | ((unsigned)(unsigned short)b << 16);
}

// ---------------- degree histogram + unique slot capture ----------------
__global__ __launch_bounds__(256) void deg_hist_k(const int* __restrict__ col,
                                                  int* __restrict__ deg,
                                                  int* __restrict__ slot, int E) {
    int e = blockIdx.x * 256 + threadIdx.x;
    if (e < E) slot[e] = atomicAdd(&deg[col[e]], 1);
}

// ---------------- scan1 + degree finish (fused) ----------------
__global__ __launch_bounds__(256) void scan1_k(const int* __restrict__ deg,
                                               int* __restrict__ incl,
                                               int* __restrict__ partial,
                                               float* __restrict__ dis,
                                               float* __restrict__ dinv, int N) {
    int i = blockIdx.x * 256 + threadIdx.x;
    int lane = threadIdx.x & 63;
    int wid = threadIdx.x >> 6;
    int d0 = (i < N) ? deg[i] : 0;
    if (i < N) {
        double d = (double)d0 + 1.0;
        dis[i]  = (float)(1.0 / sqrt(d));
        dinv[i] = (float)(1.0 / d);
    }
    int s = d0;
#pragma unroll
    for (int off = 1; off < 64; off <<= 1) {
        int t = __shfl_up(s, off);
        if (lane >= off) s += t;
    }
    __shared__ int wsum[4];
    if (lane == 63) wsum[wid] = s;
    __syncthreads();
    if (threadIdx.x == 0) {
        int run = 0;
#pragma unroll
        for (int w = 0; w < 4; ++w) { int t = wsum[w]; wsum[w] = run; run += t; }
    }
    __syncthreads();
    s += wsum[wid];
    if (i < N) incl[i] = s;
    if (threadIdx.x == 255) partial[blockIdx.x] = s;
}

__global__ __launch_bounds__(512) void scan2_k(int* __restrict__ partial, int NB) {
    __shared__ int sm[512];
    int t = threadIdx.x;
    sm[t] = (t < NB) ? partial[t] : 0;
    __syncthreads();
    for (int off = 1; off < 512; off <<= 1) {
        int v = (t >= off) ? sm[t - off] : 0;
        __syncthreads();
        sm[t] += v;
        __syncthreads();
    }
    if (t < NB) partial[t] = (t == 0) ? 0 : sm[t - 1];
}

__global__ __launch_bounds__(256) void scan3_k(const int* __restrict__ deg,
                                               const int* __restrict__ incl,
                                               const int* __restrict__ partial,
                                               int* __restrict__ row_ptr, int N) {
    int i = blockIdx.x * 256 + threadIdx.x;
    if (i < N) {
        int off = partial[blockIdx.x];
        row_ptr[i] = incl[i] - deg[i] + off;
        if (i == N - 1) row_ptr[N] = incl[i] + off;
    }
}

// ---------------- CSR fill: atomic-free (slot from deg_hist) ----------------
__global__ __launch_bounds__(256) void fill_k(const int* __restrict__ row,
                                              const int* __restrict__ col,
                                              const int* __restrict__ slot,
                                              const float* __restrict__ dis,
                                              const int* __restrict__ row_ptr,
                                              int2* __restrict__ csr, int E) {
    int e = blockIdx.x * 256 + threadIdx.x;
    if (e >= E) return;
    int c = col[e];
    int r = row[e];
    float nrm = dis[r] * dis[c];
    csr[row_ptr[c] + slot[e]] = make_int2(r, __float_as_int(nrm));
}

// ---------------- X fp32 -> fp16 ----------------
__global__ __launch_bounds__(256) void xcvt_k(const float* __restrict__ X,
                                              _Float16* __restrict__ xh, int n4) {
    int i = blockIdx.x * 256 + threadIdx.x;
    if (i < n4) {
        float4 v = *reinterpret_cast<const float4*>(X + (size_t)i * 4);
        h16x4 h = {(_Float16)v.x, (_Float16)v.y, (_Float16)v.z, (_Float16)v.w};
        *reinterpret_cast<h16x4*>(xh + (size_t)i * 4) = h;
    }
}

// ---------------- W pre-split: W[K][128] -> T_hi/lo[n][k] (bf16 shorts) ----------------
__global__ __launch_bounds__(256) void wsplit_k(const float* __restrict__ W,
                                                short* __restrict__ Thi,
                                                short* __restrict__ Tlo, int K) {
    int idx = blockIdx.x * 256 + threadIdx.x;
    if (idx < K * 128) {
        int k = idx >> 7, n = idx & 127;
        short h, l; split_bf16(W[idx], h, l);
        Thi[n * K + k] = h; Tlo[n * K + k] = l;
    }
}

// ---------------- chunked split-bf16 MFMA GEMM (fp32 or fp16 input A) ----------------
template<int K, bool RELU, bool BIAS, bool INH, bool OUTH>
__global__ __launch_bounds__(256) void gemm_mfma2(const float* __restrict__ XF,
                                                  const _Float16* __restrict__ XH,
                                                  const short* __restrict__ WThi,
                                                  const short* __restrict__ WTlo,
                                                  const float* __restrict__ b,
                                                  float* __restrict__ outF,
                                                  _Float16* __restrict__ outH, int N) {
    constexpr int KP = 40;
    __shared__ short ahi[128][KP], alo[128][KP];
    __shared__ short bhi[128][KP], blo[128][KP];
    const int tid = threadIdx.x;
    const int wid = tid >> 6, lane = tid & 63;
    const int lr = lane & 15;
    const int lk = (lane >> 4) * 8;
    const int m0b = blockIdx.x * 128;

    f32x4 acc[2][8];
#pragma unroll
    for (int rt = 0; rt < 2; ++rt)
#pragma unroll
        for (int ct = 0; ct < 8; ++ct) acc[rt][ct] = (f32x4){0.f, 0.f, 0.f, 0.f};

    for (int ch = 0; ch < K / 32; ++ch) {
        __syncthreads();
        if (INH) {
            // stage A chunk from fp16: 128 rows x 32 halves via h16x8
#pragma unroll
            for (int i = 0; i < 2; ++i) {
                int f = tid + i * 256;           // 0..511
                int r = f >> 2, k8 = (f & 3) * 8;
                int grow = m0b + r;
                float v[8] = {0.f, 0.f, 0.f, 0.f, 0.f, 0.f, 0.f, 0.f};
                if (grow < N) {
                    h16x8 hv = *reinterpret_cast<const h16x8*>(XH + (size_t)grow * K + ch * 32 + k8);
#pragma unroll
                    for (int j = 0; j < 8; ++j) v[j] = (float)hv[j];
                }
#pragma unroll
                for (int jj = 0; jj < 4; ++jj) {
                    float a0 = RELU ? fmaxf(v[2 * jj], 0.f) : v[2 * jj];
                    float a1 = RELU ? fmaxf(v[2 * jj + 1], 0.f) : v[2 * jj + 1];
                    short hA, lA, hB, lB;
                    split_bf16(a0, hA, lA); split_bf16(a1, hB, lB);
                    *reinterpret_cast<unsigned*>(&ahi[r][k8 + 2 * jj]) = pack2(hA, hB);
                    *reinterpret_cast<unsigned*>(&alo[r][k8 + 2 * jj]) = pack2(lA, lB);
                }
            }
        } else {
            // stage A chunk from fp32: 128 rows x 32 floats via float4
#pragma unroll
            for (int i = 0; i < 4; ++i) {
                int f = tid + i * 256;           // 0..1023
                int r = f >> 3, kq = f & 7;
                int grow = m0b + r;
                float4 v = make_float4(0.f, 0.f, 0.f, 0.f);
                if (grow < N) v = *reinterpret_cast<const float4*>(XF + (size_t)grow * K + ch * 32 + kq * 4);
                if (RELU) {
                    v.x = fmaxf(v.x, 0.f); v.y = fmaxf(v.y, 0.f);
                    v.z = fmaxf(v.z, 0.f); v.w = fmaxf(v.w, 0.f);
                }
                short hA, lA, hB, lB;
                split_bf16(v.x, hA, lA); split_bf16(v.y, hB, lB);
                *reinterpret_cast<unsigned*>(&ahi[r][kq * 4])     = pack2(hA, hB);
                *reinterpret_cast<unsigned*>(&alo[r][kq * 4])     = pack2(lA, lB);
                split_bf16(v.z, hA, lA); split_bf16(v.w, hB, lB);
                *reinterpret_cast<unsigned*>(&ahi[r][kq * 4 + 2]) = pack2(hA, hB);
                *reinterpret_cast<unsigned*>(&alo[r][kq * 4 + 2]) = pack2(lA, lB);
            }
        }
        // stage B chunk: pre-split WT rows n=0..127, 32 shorts/row via 16B copies
#pragma unroll
        for (int i = 0; i < 2; ++i) {
            int f = tid + i * 256;               // 0..511
            int n = f >> 2, k8 = (f & 3) * 8;
            *reinterpret_cast<uint4*>(&bhi[n][k8]) =
                *reinterpret_cast<const uint4*>(WThi + (size_t)n * K + ch * 32 + k8);
            *reinterpret_cast<uint4*>(&blo[n][k8]) =
                *reinterpret_cast<const uint4*>(WTlo + (size_t)n * K + ch * 32 + k8);
        }
        __syncthreads();

        bf16x8 Ahi[2], Alo[2];
#pragma unroll
        for (int rt = 0; rt < 2; ++rt) {
            int arow = wid * 32 + rt * 16 + lr;
            Ahi[rt] = *reinterpret_cast<const bf16x8*>(&ahi[arow][lk]);
            Alo[rt] = *reinterpret_cast<const bf16x8*>(&alo[arow][lk]);
        }
#pragma unroll
        for (int ct = 0; ct < 8; ++ct) {
            bf16x8 Bhi = *reinterpret_cast<const bf16x8*>(&bhi[ct * 16 + lr][lk]);
            bf16x8 Blo = *reinterpret_cast<const bf16x8*>(&blo[ct * 16 + lr][lk]);
#pragma unroll
            for (int rt = 0; rt < 2; ++rt) {
                acc[rt][ct] = __builtin_amdgcn_mfma_f32_16x16x32_bf16(Ahi[rt], Bhi, acc[rt][ct], 0, 0, 0);
                acc[rt][ct] = __builtin_amdgcn_mfma_f32_16x16x32_bf16(Ahi[rt], Blo, acc[rt][ct], 0, 0, 0);
                acc[rt][ct] = __builtin_amdgcn_mfma_f32_16x16x32_bf16(Alo[rt], Bhi, acc[rt][ct], 0, 0, 0);
            }
        }
    }

    const int r0 = (lane >> 4) * 4;
#pragma unroll
    for (int ct = 0; ct < 8; ++ct) {
        float bias = BIAS ? b[ct * 16 + lr] : 0.f;
#pragma unroll
        for (int rt = 0; rt < 2; ++rt) {
#pragma unroll
            for (int r = 0; r < 4; ++r) {
                int rowi = m0b + wid * 32 + rt * 16 + r0 + r;
                if (rowi < N) {
                    float val = acc[rt][ct][r] + bias;
                    if (OUTH) outH[(size_t)rowi * HDIM + ct * 16 + lr] = (_Float16)val;
                    else      outF[(size_t)rowi * HDIM + ct * 16 + lr] = val;
                }
            }
        }
    }
}

// ---------------- 32-dim input gather (octant, fp16 X, int2 csr w/ norm) ----------------
__global__ __launch_bounds__(256) void gather_x_k(const int* __restrict__ row_ptr,
                                                  const int2* __restrict__ csr,
                                                  const float* __restrict__ dinv,
                                                  const _Float16* __restrict__ xh,
                                                  float* __restrict__ Y, int N) {
    int idx = blockIdx.x * 256 + threadIdx.x;
    int c = idx >> 3;
    if (c >= N) return;
    int hq = idx & 7;
    int j0 = row_ptr[c], j1 = row_ptr[c + 1];
    float di = dinv[c];
    h16x4 xc = *reinterpret_cast<const h16x4*>(xh + (size_t)c * 32 + hq * 4);
    float4 acc = make_float4(di * (float)xc[0], di * (float)xc[1],
                             di * (float)xc[2], di * (float)xc[3]);
    int j = j0;
    for (; j + 3 < j1; j += 4) {
        int2 e0 = csr[j], e1 = csr[j + 1], e2 = csr[j + 2], e3 = csr[j + 3];
        h16x4 v0 = *reinterpret_cast<const h16x4*>(xh + (size_t)e0.x * 32 + hq * 4);
        h16x4 v1 = *reinterpret_cast<const h16x4*>(xh + (size_t)e1.x * 32 + hq * 4);
        h16x4 v2 = *reinterpret_cast<const h16x4*>(xh + (size_t)e2.x * 32 + hq * 4);
        h16x4 v3 = *reinterpret_cast<const h16x4*>(xh + (size_t)e3.x * 32 + hq * 4);
        float n0 = __int_as_float(e0.y), n1 = __int_as_float(e1.y);
        float n2 = __int_as_float(e2.y), n3 = __int_as_float(e3.y);
        acc.x += n0 * (float)v0[0] + n1 * (float)v1[0] + n2 * (float)v2[0] + n3 * (float)v3[0];
        acc.y += n0 * (float)v0[1] + n1 * (float)v1[1] + n2 * (float)v2[1] + n3 * (float)v3[1];
        acc.z += n0 * (float)v0[2] + n1 * (float)v1[2] + n2 * (float)v2[2] + n3 * (float)v3[2];
        acc.w += n0 * (float)v0[3] + n1 * (float)v1[3] + n2 * (float)v2[3] + n3 * (float)v3[3];
    }
    for (; j < j1; ++j) {
        int2 en = csr[j];
        float nrm = __int_as_float(en.y);
        h16x4 v = *reinterpret_cast<const h16x4*>(xh + (size_t)en.x * 32 + hq * 4);
        acc.x += nrm * (float)v[0]; acc.y += nrm * (float)v[1];
        acc.z += nrm * (float)v[2]; acc.w += nrm * (float)v[3];
    }
    *reinterpret_cast<float4*>(Y + (size_t)c * 32 + hq * 4) = acc;
}

// ---------------- w3l = W3 @ Wlin ; consts[0] = b3.Wlin + blin ----------------
__global__ __launch_bounds__(128) void w3l_k(const float* __restrict__ W3,
                                             const float* __restrict__ b3,
                                             const float* __restrict__ Wlin,
                                             const float* __restrict__ blin,
                                             float* __restrict__ w3l,
                                             float* __restrict__ consts) {
    __shared__ float wl[128];
    __shared__ float red[128];
    int t = threadIdx.x;
    wl[t] = Wlin[t];
    __syncthreads();
    float a = 0.f;
    for (int j = 0; j < 128; ++j) a += W3[t * 128 + j] * wl[j];
    w3l[t] = a;
    red[t] = b3[t] * wl[t];
    __syncthreads();
    for (int off = 64; off > 0; off >>= 1) {
        if (t < off) red[t] += red[t + off];
        __syncthreads();
    }
    if (t == 0) consts[0] = red[0] + blin[0];
}

// ---------------- fused layer-2 gather (fp16 xw, int2 csr) + z projection ----------------
__global__ __launch_bounds__(256) void gather_z_k(const int* __restrict__ row_ptr,
                                                  const int2* __restrict__ csr,
                                                  const float* __restrict__ dinv,
                                                  const float* __restrict__ b,
                                                  const _Float16* __restrict__ xw,
                                                  const float* __restrict__ w3l,
                                                  float* __restrict__ z, int N) {
    int c = (blockIdx.x * 256 + threadIdx.x) >> 6;
    if (c >= N) return;
    int lane = threadIdx.x & 63;
    int g = lane >> 4;          // edge slot 0..3
    int q = lane & 15;          // 8-elem chunk of the 128-dim row
    int j0 = row_ptr[c], j1 = row_ptr[c + 1];
    float acc[8] = {0.f, 0.f, 0.f, 0.f, 0.f, 0.f, 0.f, 0.f};
    int j = j0 + g;
    for (; j + 4 < j1; j += 8) {
        int2 e0 = csr[j], e1 = csr[j + 4];
        float n0 = __int_as_float(e0.y), n1 = __int_as_float(e1.y);
        h16x8 v0 = *reinterpret_cast<const h16x8*>(xw + (size_t)e0.x * HDIM + q * 8);
        h16x8 v1 = *reinterpret_cast<const h16x8*>(xw + (size_t)e1.x * HDIM + q * 8);
#pragma unroll
        for (int k = 0; k < 8; ++k) acc[k] += n0 * (float)v0[k] + n1 * (float)v1[k];
    }
    for (; j < j1; j += 4) {
        int2 en = csr[j];
        float nrm = __int_as_float(en.y);
        h16x8 v = *reinterpret_cast<const h16x8*>(xw + (size_t)en.x * HDIM + q * 8);
#pragma unroll
        for (int k = 0; k < 8; ++k) acc[k] += nrm * (float)v[k];
    }
#pragma unroll
    for (int k = 0; k < 8; ++k) {
        acc[k] += __shfl_xor(acc[k], 16);
        acc[k] += __shfl_xor(acc[k], 32);
    }
    h16x8 xc = *reinterpret_cast<const h16x8*>(xw + (size_t)c * HDIM + q * 8);
    float di = dinv[c];
    float4 b0 = *reinterpret_cast<const float4*>(b + q * 8);
    float4 b1 = *reinterpret_cast<const float4*>(b + q * 8 + 4);
    float4 w0 = *reinterpret_cast<const float4*>(w3l + q * 8);
    float4 w1 = *reinterpret_cast<const float4*>(w3l + q * 8 + 4);
    const float bb[8] = {b0.x, b0.y, b0.z, b0.w, b1.x, b1.y, b1.z, b1.w};
    const float ww[8] = {w0.x, w0.y, w0.z, w0.w, w1.x, w1.y, w1.z, w1.w};
    float t = 0.f;
#pragma unroll
    for (int k = 0; k < 8; ++k)
        t += fmaxf(di * (float)xc[k] + bb[k] + acc[k], 0.f) * ww[k];
#pragma unroll
    for (int off = 1; off < 16; off <<= 1) t += __shfl_xor(t, off);
    if (lane == 0) z[c] = t;
}

// ---------------- scalar layer-3 gather (int2 csr) ----------------
__global__ __launch_bounds__(256) void gather_s_k(const int* __restrict__ row_ptr,
                                                  const int2* __restrict__ csr,
                                                  const float* __restrict__ dinv,
                                                  const float* __restrict__ z,
                                                  float* __restrict__ s, int N) {
    int c = blockIdx.x * 256 + threadIdx.x;
    if (c >= N) return;
    int j0 = row_ptr[c], j1 = row_ptr[c + 1];
    float acc = dinv[c] * z[c];
    for (int j = j0; j < j1; ++j) {
        int2 en = csr[j];
        acc += __int_as_float(en.y) * z[en.x];
    }
    s[c] = acc;
}

// ---------------- graph start offsets (batch is sorted) ----------------
__global__ __launch_bounds__(256) void gstart_k(const int* __restrict__ batch,
                                                int* __restrict__ start, int N, int G) {
    int n = blockIdx.x * 256 + threadIdx.x;
    if (n > N) return;
    if (n < N) {
        int b = batch[n];
        int prev = (n == 0) ? -1 : batch[n - 1];
        for (int g = prev + 1; g <= b; ++g) start[g] = n;
    } else {
        int prev = batch[N - 1];
        for (int g = prev + 1; g <= G; ++g) start[g] = N;
    }
}

// ---------------- final: out[g] = mean_{c in g} s[c] + consts[0] ----------------
__global__ __launch_bounds__(256) void final_z_k(const float* __restrict__ s,
                                                 const int* __restrict__ start,
                                                 const float* __restrict__ consts,
                                                 const float* __restrict__ blin,
                                                 float* __restrict__ out, int G) {
    int g = blockIdx.x * 4 + (threadIdx.x >> 6);
    int lane = threadIdx.x & 63;
    if (g >= G) return;
    int a = start[g], e = start[g + 1];
    float acc = 0.f;
    for (int n = a + lane; n < e; n += 64) acc += s[n];
#pragma unroll
    for (int off = 32; off > 0; off >>= 1) acc += __shfl_down(acc, off);
    if (lane == 0) out[g] = (e > a) ? acc / (float)(e - a) + consts[0] : blin[0];
}

extern "C" void kernel_launch(void* const* d_in, const int* in_sizes, int n_in,
                              void* d_out, int out_size, void* d_ws, size_t ws_size,
                              hipStream_t stream) {
    const float* x    = (const float*)d_in[0];
    const float* W1   = (const float*)d_in[1];
    const float* b1   = (const float*)d_in[2];
    const float* W2   = (const float*)d_in[3];
    const float* b2   = (const float*)d_in[4];
    const float* W3   = (const float*)d_in[5];
    const float* b3   = (const float*)d_in[6];
    const float* Wlin = (const float*)d_in[7];
    const float* blin = (const float*)d_in[8];
    const int* ei     = (const int*)d_in[9];
    const int* batch  = (const int*)d_in[10];

    const int N = in_sizes[10];
    const int E = in_sizes[9] / 2;
    const int G = out_size;
    const size_t NH = (size_t)N * HDIM;
    const int NB = (N + 255) / 256;

    const int* row = ei;
    const int* col = ei + E;

    int2* csr      = (int2*)d_ws;                    // [E] {src, nrm}
    _Float16* xh   = (_Float16*)(csr + E);           // [N,32] fp16
    float* Y       = (float*)(xh + (size_t)N * 32);  // [N,32] fp32
    _Float16* h1   = (_Float16*)(Y + (size_t)N * 32);// [N,128] fp16
    _Float16* xwh  = h1 + NH;                        // [N,128] fp16
    float* dis     = (float*)(xwh + NH);             // [N]
    float* dinv    = dis + N;                        // [N]
    float* zbuf    = dinv + N;                       // [N]
    float* sbuf    = zbuf + N;                       // [N]
    float* w3l     = sbuf + N;                       // [128]
    float* consts  = w3l + 128;                      // [4]
    short* w1hi    = (short*)(consts + 4);           // [128*32]
    short* w1lo    = w1hi + 128 * 32;
    short* w2hi    = w1lo + 128 * 32;                // [128*128]
    short* w2lo    = w2hi + 128 * 128;
    int* deg_i     = (int*)(w2lo + 128 * 128);       // [N]
    int* row_ptr   = deg_i + N;                      // [N+1]
    int* slot      = row_ptr + N + 1;                // [E]
    int* gstart    = slot + E;                       // [G+1]
    int* incl      = gstart + G + 1;                 // [N]
    int* partial   = incl + N;                       // [NB]

    float* outf = (float*)d_out;

    // ---- CSR build + weight prep ----
    hipMemsetAsync(deg_i, 0, (size_t)N * sizeof(int), stream);
    deg_hist_k<<<(E + 255) / 256, 256, 0, stream>>>(col, deg_i, slot, E);
    scan1_k<<<NB, 256, 0, stream>>>(deg_i, incl, partial, dis, dinv, N);
    scan2_k<<<1, 512, 0, stream>>>(partial, NB);
    scan3_k<<<NB, 256, 0, stream>>>(deg_i, incl, partial, row_ptr, N);
    fill_k<<<(E + 255) / 256, 256, 0, stream>>>(row, col, slot, dis, row_ptr, csr, E);
    gstart_k<<<(N + 256) / 256, 256, 0, stream>>>(batch, gstart, N, G);
    xcvt_k<<<(N * 8 + 255) / 256, 256, 0, stream>>>(x, xh, N * 8);
    wsplit_k<<<(32 * 128 + 255) / 256, 256, 0, stream>>>(W1, w1hi, w1lo, 32);
    wsplit_k<<<(128 * 128 + 255) / 256, 256, 0, stream>>>(W2, w2hi, w2lo, 128);
    w3l_k<<<1, 128, 0, stream>>>(W3, b3, Wlin, blin, w3l, consts);

    const int mfma_grid = (N + 127) / 128;
    const int wave_grid = (N + 3) / 4;

    // layer 1 (aggregate-first): Y = A_hat xh (fp32 acc) ; h1 = Y W1 + b1 (fp16 out)
    gather_x_k<<<(N * 8 + 255) / 256, 256, 0, stream>>>(row_ptr, csr, dinv, xh, Y, N);
    gemm_mfma2<32, false, true, false, true><<<mfma_grid, 256, 0, stream>>>(Y, nullptr, w1hi, w1lo, b1, nullptr, h1, N);
    // layer 2: xwh = relu(h1) W2 (fp16 in/out) ; fused gather(+b2) + z = relu(h2).w3l
    gemm_mfma2<128, true, false, true, true><<<mfma_grid, 256, 0, stream>>>(nullptr, h1, w2hi, w2lo, nullptr, nullptr, xwh, N);
    gather_z_k<<<wave_grid, 256, 0, stream>>>(row_ptr, csr, dinv, b2, xwh, w3l, zbuf, N);
    // layer 3 (collapsed): s = dinv*z + A-gather(z)
    gather_s_k<<<(N + 255) / 256, 256, 0, stream>>>(row_ptr, csr, dinv, zbuf, sbuf, N);
    // final: segment mean + consts
    final_z_k<<<(G + 3) / 4, 256, 0, stream>>>(sbuf, gstart, consts, blin, outf, G);
}